// Round 1
// baseline (132.737 us; speedup 1.0000x reference)
//
#include <hip/hip_runtime.h>
#include <math.h>

// Problem constants (B,C,H,W) = (32,1,384,384), fp32 in/out, scalar output.
#define NB   32
#define NH   384
#define NW   384
#define NPIX (NH * NW)
#define KRAD 15
#define KSZ  31
#define INV_DIV (1.0f / 961.0f)
#define EPSV 1e-7f

// ---------------------------------------------------------------------------
// Kernel A: horizontal 31-tap box SUM of target, one block = 4 rows.
// Also zeroes the per-image accumulators (block 0) so kernel B can atomicAdd.
// ---------------------------------------------------------------------------
__global__ __launch_bounds__(256) void hbox_kernel(
    const float* __restrict__ tgt,
    float* __restrict__ hsum,
    float* __restrict__ accum)
{
    if (blockIdx.x == 0 && threadIdx.x < 128) accum[threadIdx.x] = 0.0f;

    const int ROWS = 4;
    const int PW = NW + 2 * KRAD;          // 414 padded width
    __shared__ float sp[ROWS][NW + 2 * KRAD];

    const int row0 = blockIdx.x * ROWS;    // global row index into B*H rows

    // Cooperative load: 4 rows with zero pads, coalesced across threads.
    for (int i = threadIdx.x; i < ROWS * PW; i += 256) {
        int r   = i / PW;
        int j   = i % PW;
        int col = j - KRAD;
        float v = 0.0f;
        if (col >= 0 && col < NW) v = tgt[(size_t)(row0 + r) * NW + col];
        sp[r][j] = v;
    }
    __syncthreads();

    // Each thread: 6 consecutive outputs via register sliding window.
    const int r  = threadIdx.x >> 6;       // 0..3  (row within block)
    const int l  = threadIdx.x & 63;       // 0..63 (lane)
    const int x0 = l * 6;                  // first output column

    float w = 0.0f;
    #pragma unroll
    for (int k = 0; k < KSZ; ++k) w += sp[r][x0 + k];

    float* out = hsum + (size_t)(row0 + r) * NW + x0;
    out[0] = w;
    #pragma unroll
    for (int i = 1; i < 6; ++i) {
        w += sp[r][x0 + KSZ - 1 + i] - sp[r][x0 + i - 1];
        out[i] = w;
    }
}

// ---------------------------------------------------------------------------
// Kernel B: vertical 31-tap box sum (sliding window down a column) fused with
// weit / BCE / sigmoid and the four per-image reductions.
// grid = NB images x 8 row-tiles (48 rows each); block = 384 threads (1/col).
// ---------------------------------------------------------------------------
__global__ __launch_bounds__(384) void fused_kernel(
    const float* __restrict__ xin,
    const float* __restrict__ tgt,
    const float* __restrict__ hsum,
    float* __restrict__ accum)
{
    const int YT = 48;
    const int b  = blockIdx.x >> 3;
    const int y0 = (blockIdx.x & 7) * YT;
    const int x  = threadIdx.x;            // column 0..383

    const float* __restrict__ hs = hsum + (size_t)b * NPIX;
    const float* __restrict__ tb = tgt  + (size_t)b * NPIX;
    const float* __restrict__ ib = xin  + (size_t)b * NPIX;

    // Init vertical window sum for output row y0.
    float w = 0.0f;
    {
        int rlo = y0 - KRAD; if (rlo < 0)      rlo = 0;
        int rhi = y0 + KRAD; if (rhi > NH - 1) rhi = NH - 1;
        for (int rr = rlo; rr <= rhi; ++rr) w += hs[(size_t)rr * NW + x];
    }

    float s_w = 0.0f, s_wb = 0.0f, s_i = 0.0f, s_u = 0.0f;

    for (int y = y0; y < y0 + YT; ++y) {
        const float bavg = w * INV_DIV;
        const float t = tb[(size_t)y * NW + x];
        const float v = ib[(size_t)y * NW + x];

        const float weit = 1.0f + 5.0f * fabsf(bavg - t);

        const float e    = expf(-fabsf(v));           // shared by BCE and sigmoid
        const float wbce = fmaxf(v, 0.0f) - v * t + log1pf(e);
        const float p    = (v >= 0.0f) ? 1.0f / (1.0f + e) : e / (1.0f + e);

        s_w  += weit;
        s_wb += weit * wbce;
        s_i  += p * t * weit;
        s_u  += (p + t) * weit;

        // Slide window: center y -> y+1 adds row y+16, drops row y-15.
        const int add_r = y + KRAD + 1;
        const int sub_r = y - KRAD;
        if (add_r < NH)  w += hs[(size_t)add_r * NW + x];
        if (sub_r >= 0)  w -= hs[(size_t)sub_r * NW + x];
    }

    // Block reduction: wave shuffle (64-lane), then LDS across 6 waves.
    #pragma unroll
    for (int off = 32; off > 0; off >>= 1) {
        s_w  += __shfl_down(s_w,  off);
        s_wb += __shfl_down(s_wb, off);
        s_i  += __shfl_down(s_i,  off);
        s_u  += __shfl_down(s_u,  off);
    }
    __shared__ float red[6][4];
    const int lane = threadIdx.x & 63;
    const int wv   = threadIdx.x >> 6;
    if (lane == 0) {
        red[wv][0] = s_w; red[wv][1] = s_wb; red[wv][2] = s_i; red[wv][3] = s_u;
    }
    __syncthreads();
    if (threadIdx.x < 4) {
        float acc = 0.0f;
        #pragma unroll
        for (int i = 0; i < 6; ++i) acc += red[i][threadIdx.x];
        atomicAdd(&accum[b * 4 + threadIdx.x], acc);
    }
}

// ---------------------------------------------------------------------------
// Kernel C: per-image wbce/wiou and the mean over 32 images.
// ---------------------------------------------------------------------------
__global__ __launch_bounds__(64) void finalize_kernel(
    const float* __restrict__ accum,
    float* __restrict__ out)
{
    __shared__ float ls[NB];
    const int t = threadIdx.x;
    if (t < NB) {
        const float sw  = accum[4 * t + 0];
        const float swb = accum[4 * t + 1];
        const float si  = accum[4 * t + 2];
        const float su  = accum[4 * t + 3];
        const float wbce = swb / sw;
        const float wiou = 1.0f - (si + 1.0f) / (su - si + 1.0f + EPSV);
        ls[t] = wbce + wiou;
    }
    __syncthreads();
    if (t == 0) {
        float s = 0.0f;
        #pragma unroll
        for (int i = 0; i < NB; ++i) s += ls[i];
        out[0] = s * (1.0f / (float)NB);
    }
}

// ---------------------------------------------------------------------------
extern "C" void kernel_launch(void* const* d_in, const int* in_sizes, int n_in,
                              void* d_out, int out_size, void* d_ws, size_t ws_size,
                              hipStream_t stream)
{
    const float* xin = (const float*)d_in[0];   // "input"  (logits)
    const float* tgt = (const float*)d_in[1];   // "target"
    float* hsum  = (float*)d_ws;                // NB*NPIX floats (18.9 MB)
    float* accum = hsum + (size_t)NB * NPIX;    // 128 floats

    hbox_kernel    <<<(NB * NH) / 4, 256, 0, stream>>>(tgt, hsum, accum);
    fused_kernel   <<<NB * 8,        384, 0, stream>>>(xin, tgt, hsum, accum);
    finalize_kernel<<<1,             64,  0, stream>>>(accum, (float*)d_out);
}

// Round 3
// 121.213 us; speedup vs baseline: 1.0951x; 1.0951x over previous
//
#include <hip/hip_runtime.h>
#include <math.h>

// Problem constants (B,C,H,W) = (32,1,384,384), fp32 in/out, scalar output.
#define NB   32
#define NH   384
#define NW   384
#define NPIX (NH * NW)
#define KRAD 15
#define KSZ  31
#define INV_DIV (1.0f / 961.0f)
#define EPSV 1e-7f

// ---------------------------------------------------------------------------
// Kernel A: horizontal 31-tap box SUM of target, one block = 4 rows.
// float4 staging loads, register sliding window (6 outputs/thread, stride-6
// LDS reads = 2 lanes/bank = free), LDS transpose for coalesced float4 stores.
// Block 0 also zeroes the per-image accumulators for kernel B's atomicAdd.
// ---------------------------------------------------------------------------
__global__ __launch_bounds__(256) void hbox_kernel(
    const float* __restrict__ tgt,
    float* __restrict__ hsum,
    float* __restrict__ accum)
{
    if (blockIdx.x == 0 && threadIdx.x < 128) accum[threadIdx.x] = 0.0f;

    // Left pad = 16 (one unused slot) so payload starts 16B-aligned.
    // sp[r][16 + c] = tgt[row][c]; window for output x = sp[x+1 .. x+31].
    const int PW = 16 + NW + 16;               // 416 (multiple of 32)
    __shared__ float sp[4][16 + NW + 16];

    const int row0 = blockIdx.x * 4;
    const int tid  = threadIdx.x;

    // Zero the pads: 4 rows x 32 pad slots = 128 threads.
    if (tid < 128) {
        int r = tid >> 5, j = tid & 31;
        int col = (j < 16) ? j : (16 + NW + (j - 16));
        sp[r][col] = 0.0f;
    }
    // Stage 4 rows x 96 quads, float4, coalesced.
    for (int i = tid; i < 384; i += 256) {
        int r = i / 96, q = i % 96;
        float4 v = *reinterpret_cast<const float4*>(&tgt[(size_t)(row0 + r) * NW + q * 4]);
        *reinterpret_cast<float4*>(&sp[r][16 + q * 4]) = v;
    }
    __syncthreads();

    // Each thread: 6 consecutive outputs via register sliding window.
    const int r  = tid >> 6;                   // 0..3
    const int l  = tid & 63;                   // 0..63
    const int x0 = l * 6;                      // first output column

    float res[6];
    float w = 0.0f;
    #pragma unroll
    for (int k = 0; k < KSZ; ++k) w += sp[r][x0 + 1 + k];
    res[0] = w;
    #pragma unroll
    for (int i = 1; i < 6; ++i) {
        w += sp[r][x0 + i + 31] - sp[r][x0 + i];
        res[i] = w;
    }
    __syncthreads();

    // Transpose through LDS (reuse sp as [4][384]) for coalesced stores.
    float* ob = &sp[0][0];
    #pragma unroll
    for (int i = 0; i < 6; ++i) ob[r * NW + x0 + i] = res[i];
    __syncthreads();
    for (int i = tid; i < 384; i += 256) {
        int rr = i / 96, q = i % 96;
        float4 v = *reinterpret_cast<float4*>(&ob[rr * NW + q * 4]);
        *reinterpret_cast<float4*>(&hsum[(size_t)(row0 + rr) * NW + q * 4]) = v;
    }
}

// ---------------------------------------------------------------------------
// Kernel B: vertical 31-tap box sum fused with weit/BCE/sigmoid + reductions.
// Block = 384 threads = 96 column-quads x 4 row-groups; each thread owns a
// float4 of columns and slides a 6-row vertical window -> tile = 24 rows.
// Grid = 32 images x 16 tiles = 512 blocks (2 blocks/CU, 12 waves/CU, 4x ILP).
// ---------------------------------------------------------------------------
__global__ __launch_bounds__(384) void fused_kernel(
    const float* __restrict__ xin,
    const float* __restrict__ tgt,
    const float* __restrict__ hsum,
    float* __restrict__ accum)
{
    const int YTG = 6;
    const int b    = blockIdx.x >> 4;          // image
    const int tile = blockIdx.x & 15;          // 0..15 (24 rows each)
    const int tid  = threadIdx.x;
    const int rg   = tid / 96;                 // row-group 0..3
    const int q    = tid % 96;                 // column quad
    const int c0   = q * 4;
    const int y0   = tile * 24 + rg * YTG;     // first output row

    const float* __restrict__ hs = hsum + (size_t)b * NPIX;
    const float* __restrict__ tb = tgt  + (size_t)b * NPIX;
    const float* __restrict__ ib = xin  + (size_t)b * NPIX;

    // Init vertical window (rows y0-15 .. y0+15, clamped) for 4 columns.
    float w0 = 0.0f, w1 = 0.0f, w2 = 0.0f, w3 = 0.0f;
    #pragma unroll
    for (int k = 0; k < KSZ; ++k) {
        int rr = y0 - KRAD + k;
        if (rr >= 0 && rr < NH) {
            float4 h = *reinterpret_cast<const float4*>(&hs[(size_t)rr * NW + c0]);
            w0 += h.x; w1 += h.y; w2 += h.z; w3 += h.w;
        }
    }

    float s_w = 0.0f, s_wb = 0.0f, s_i = 0.0f, s_u = 0.0f;

    #pragma unroll
    for (int yy = 0; yy < YTG; ++yy) {
        const int y = y0 + yy;
        float4 t4 = *reinterpret_cast<const float4*>(&tb[(size_t)y * NW + c0]);
        float4 v4 = *reinterpret_cast<const float4*>(&ib[(size_t)y * NW + c0]);

        const float wv[4] = {w0, w1, w2, w3};
        const float tv[4] = {t4.x, t4.y, t4.z, t4.w};
        const float vv[4] = {v4.x, v4.y, v4.z, v4.w};
        #pragma unroll
        for (int j = 0; j < 4; ++j) {
            const float bavg = wv[j] * INV_DIV;
            const float t = tv[j];
            const float v = vv[j];
            const float weit = 1.0f + 5.0f * fabsf(bavg - t);
            const float e    = expf(-fabsf(v));         // shared by BCE & sigmoid
            const float wbce = fmaxf(v, 0.0f) - v * t + log1pf(e);
            const float p    = (v >= 0.0f) ? 1.0f / (1.0f + e) : e / (1.0f + e);
            s_w  += weit;
            s_wb += weit * wbce;
            s_i  += p * t * weit;
            s_u  += (p + t) * weit;
        }

        // Slide window: +row y+16, -row y-15.
        const int add_r = y + KRAD + 1;
        const int sub_r = y - KRAD;
        if (add_r < NH) {
            float4 h = *reinterpret_cast<const float4*>(&hs[(size_t)add_r * NW + c0]);
            w0 += h.x; w1 += h.y; w2 += h.z; w3 += h.w;
        }
        if (sub_r >= 0) {
            float4 h = *reinterpret_cast<const float4*>(&hs[(size_t)sub_r * NW + c0]);
            w0 -= h.x; w1 -= h.y; w2 -= h.z; w3 -= h.w;
        }
    }

    // Block reduction: wave shuffle (64-lane), then LDS across 6 waves.
    #pragma unroll
    for (int off = 32; off > 0; off >>= 1) {
        s_w  += __shfl_down(s_w,  off);
        s_wb += __shfl_down(s_wb, off);
        s_i  += __shfl_down(s_i,  off);
        s_u  += __shfl_down(s_u,  off);
    }
    __shared__ float red[6][4];
    const int lane = tid & 63;
    const int wv_  = tid >> 6;
    if (lane == 0) {
        red[wv_][0] = s_w; red[wv_][1] = s_wb; red[wv_][2] = s_i; red[wv_][3] = s_u;
    }
    __syncthreads();
    if (tid < 4) {
        float acc = 0.0f;
        #pragma unroll
        for (int i = 0; i < 6; ++i) acc += red[i][tid];
        atomicAdd(&accum[b * 4 + tid], acc);
    }
}

// ---------------------------------------------------------------------------
// Kernel C: per-image wbce/wiou and the mean over 32 images.
// ---------------------------------------------------------------------------
__global__ __launch_bounds__(64) void finalize_kernel(
    const float* __restrict__ accum,
    float* __restrict__ out)
{
    __shared__ float ls[NB];
    const int t = threadIdx.x;
    if (t < NB) {
        const float sw  = accum[4 * t + 0];
        const float swb = accum[4 * t + 1];
        const float si  = accum[4 * t + 2];
        const float su  = accum[4 * t + 3];
        const float wbce = swb / sw;
        const float wiou = 1.0f - (si + 1.0f) / (su - si + 1.0f + EPSV);
        ls[t] = wbce + wiou;
    }
    __syncthreads();
    if (t == 0) {
        float s = 0.0f;
        #pragma unroll
        for (int i = 0; i < NB; ++i) s += ls[i];
        out[0] = s * (1.0f / (float)NB);
    }
}

// ---------------------------------------------------------------------------
extern "C" void kernel_launch(void* const* d_in, const int* in_sizes, int n_in,
                              void* d_out, int out_size, void* d_ws, size_t ws_size,
                              hipStream_t stream)
{
    const float* xin = (const float*)d_in[0];   // "input"  (logits)
    const float* tgt = (const float*)d_in[1];   // "target"
    float* hsum  = (float*)d_ws;                // NB*NPIX floats (18.9 MB)
    float* accum = hsum + (size_t)NB * NPIX;    // 128 floats

    hbox_kernel    <<<(NB * NH) / 4, 256, 0, stream>>>(tgt, hsum, accum);
    fused_kernel   <<<NB * 16,       384, 0, stream>>>(xin, tgt, hsum, accum);
    finalize_kernel<<<1,             64,  0, stream>>>(accum, (float*)d_out);
}

// Round 10
// 114.476 us; speedup vs baseline: 1.1595x; 1.0589x over previous
//
#include <hip/hip_runtime.h>
#include <math.h>

// Problem constants (B,C,H,W) = (32,1,384,384), fp32 in/out, scalar output.
#define NB   32
#define NH   384
#define NW   384
#define NPIX (NH * NW)
#define KRAD 15
#define KSZ  31
#define INV_DIV (1.0f / 961.0f)
#define EPSV 1e-7f

// ---------------------------------------------------------------------------
// Kernel A: horizontal 31-tap box SUM of target, one block = 4 rows.
// (unchanged from round 3 — not yet observed in top-5; fused speedup this
// round will surface its true cost for the next diagnosis.)
// ---------------------------------------------------------------------------
__global__ __launch_bounds__(256) void hbox_kernel(
    const float* __restrict__ tgt,
    float* __restrict__ hsum,
    float* __restrict__ accum)
{
    if (blockIdx.x == 0 && threadIdx.x < 128) accum[threadIdx.x] = 0.0f;

    __shared__ float sp[4][16 + NW + 16];      // left pad 16 => aligned payload

    const int row0 = blockIdx.x * 4;
    const int tid  = threadIdx.x;

    if (tid < 128) {                            // zero the pads
        int r = tid >> 5, j = tid & 31;
        int col = (j < 16) ? j : (16 + NW + (j - 16));
        sp[r][col] = 0.0f;
    }
    for (int i = tid; i < 384; i += 256) {      // stage 4 rows, float4
        int r = i / 96, q = i % 96;
        float4 v = *reinterpret_cast<const float4*>(&tgt[(size_t)(row0 + r) * NW + q * 4]);
        *reinterpret_cast<float4*>(&sp[r][16 + q * 4]) = v;
    }
    __syncthreads();

    const int r  = tid >> 6;
    const int l  = tid & 63;
    const int x0 = l * 6;

    float res[6];
    float w = 0.0f;
    #pragma unroll
    for (int k = 0; k < KSZ; ++k) w += sp[r][x0 + 1 + k];
    res[0] = w;
    #pragma unroll
    for (int i = 1; i < 6; ++i) {
        w += sp[r][x0 + i + 31] - sp[r][x0 + i];
        res[i] = w;
    }
    __syncthreads();

    float* ob = &sp[0][0];                      // reuse as [4][384] for transpose
    #pragma unroll
    for (int i = 0; i < 6; ++i) ob[r * NW + x0 + i] = res[i];
    __syncthreads();
    for (int i = tid; i < 384; i += 256) {
        int rr = i / 96, q = i % 96;
        float4 v = *reinterpret_cast<float4*>(&ob[rr * NW + q * 4]);
        *reinterpret_cast<float4*>(&hsum[(size_t)(row0 + rr) * NW + q * 4]) = v;
    }
}

// ---------------------------------------------------------------------------
// Elementwise loss math shared by both fused paths.
// ---------------------------------------------------------------------------
__device__ __forceinline__ void loss_accum(float wsum, float t, float v,
                                           float& s_w, float& s_wb,
                                           float& s_i, float& s_u)
{
    const float bavg = wsum * INV_DIV;
    const float weit = 1.0f + 5.0f * fabsf(bavg - t);
    const float e    = expf(-fabsf(v));           // shared by BCE & sigmoid
    const float wbce = fmaxf(v, 0.0f) - v * t + log1pf(e);
    const float p    = (v >= 0.0f) ? 1.0f / (1.0f + e) : e / (1.0f + e);
    s_w  += weit;
    s_wb += weit * wbce;
    s_i  += p * t * weit;
    s_u  += (p + t) * weit;
}

// ---------------------------------------------------------------------------
// Kernel B (v3): scalar-column fused vertical box + loss.
// Thread = 1 column x 12 rows. Block = 384 threads = full image width.
// Grid = 32 images x 32 row-tiles = 1024 blocks -> 4 blocks/CU, 24 waves/CU.
// All loads coalesced (wave = 64 consecutive columns of one row).
// XCD swizzle: blk&7 selects XCD group; each XCD works 4 whole images so the
// hsum slice (4 x 590 KB) is L2-resident.
// __launch_bounds__(384,8): cap VGPR<=64 so 8 waves/SIMD remain possible.
// ---------------------------------------------------------------------------
__global__ __launch_bounds__(384, 8) void fused_kernel(
    const float* __restrict__ xin,
    const float* __restrict__ tgt,
    const float* __restrict__ hsum,
    float* __restrict__ accum)
{
    const int blk  = blockIdx.x;
    const int img  = ((blk & 7) << 2) | ((blk >> 3) & 3);   // 4 images per XCD
    const int tile = blk >> 5;                              // 0..31
    const int x    = threadIdx.x;                           // column 0..383
    const int y0   = tile * 12;

    const float* __restrict__ hs = hsum + (size_t)img * NPIX + x;
    const float* __restrict__ tb = tgt  + (size_t)img * NPIX + x;
    const float* __restrict__ ib = xin  + (size_t)img * NPIX + x;

    float s_w = 0.0f, s_wb = 0.0f, s_i = 0.0f, s_u = 0.0f;
    float w;

    const bool interior = (tile >= 2) && (tile <= 29);
    if (interior) {
        // ---- fast path: no bounds checks anywhere ----
        float wa = 0.0f, wb = 0.0f, wc = 0.0f, wd = 0.0f;   // 4-way ILP init
        #pragma unroll
        for (int k = 0; k < 28; k += 4) {
            wa += hs[(y0 - KRAD + k + 0) * NW];
            wb += hs[(y0 - KRAD + k + 1) * NW];
            wc += hs[(y0 - KRAD + k + 2) * NW];
            wd += hs[(y0 - KRAD + k + 3) * NW];
        }
        wa += hs[(y0 + 13) * NW];
        wb += hs[(y0 + 14) * NW];
        wc += hs[(y0 + 15) * NW];
        w = (wa + wb) + (wc + wd);

        #pragma unroll
        for (int yy = 0; yy < 12; ++yy) {
            const int y = y0 + yy;
            const float t    = tb[y * NW];
            const float v    = ib[y * NW];
            const float hadd = hs[(y + KRAD + 1) * NW];
            const float hsub = hs[(y - KRAD) * NW];
            loss_accum(w, t, v, s_w, s_wb, s_i, s_u);
            w += hadd - hsub;
        }
    } else {
        // ---- edge path (tiles 0,1,30,31): predicated window rows ----
        w = 0.0f;
        #pragma unroll
        for (int k = 0; k < KSZ; ++k) {
            const int rr = y0 - KRAD + k;
            if (rr >= 0 && rr < NH) w += hs[rr * NW];
        }
        #pragma unroll
        for (int yy = 0; yy < 12; ++yy) {
            const int y = y0 + yy;
            const float t = tb[y * NW];
            const float v = ib[y * NW];
            loss_accum(w, t, v, s_w, s_wb, s_i, s_u);
            const int ra = y + KRAD + 1;
            const int rs = y - KRAD;
            if (ra < NH)  w += hs[ra * NW];
            if (rs >= 0)  w -= hs[rs * NW];
        }
    }

    // Block reduction: 64-lane shuffle, then LDS across 6 waves.
    #pragma unroll
    for (int off = 32; off > 0; off >>= 1) {
        s_w  += __shfl_down(s_w,  off);
        s_wb += __shfl_down(s_wb, off);
        s_i  += __shfl_down(s_i,  off);
        s_u  += __shfl_down(s_u,  off);
    }
    __shared__ float red[6][4];
    const int lane = threadIdx.x & 63;
    const int wv   = threadIdx.x >> 6;
    if (lane == 0) {
        red[wv][0] = s_w; red[wv][1] = s_wb; red[wv][2] = s_i; red[wv][3] = s_u;
    }
    __syncthreads();
    if (threadIdx.x < 4) {
        float acc = 0.0f;
        #pragma unroll
        for (int i = 0; i < 6; ++i) acc += red[i][threadIdx.x];
        atomicAdd(&accum[img * 4 + threadIdx.x], acc);
    }
}

// ---------------------------------------------------------------------------
// Kernel C: per-image wbce/wiou and the mean over 32 images.
// ---------------------------------------------------------------------------
__global__ __launch_bounds__(64) void finalize_kernel(
    const float* __restrict__ accum,
    float* __restrict__ out)
{
    __shared__ float ls[NB];
    const int t = threadIdx.x;
    if (t < NB) {
        const float sw  = accum[4 * t + 0];
        const float swb = accum[4 * t + 1];
        const float si  = accum[4 * t + 2];
        const float su  = accum[4 * t + 3];
        const float wbce = swb / sw;
        const float wiou = 1.0f - (si + 1.0f) / (su - si + 1.0f + EPSV);
        ls[t] = wbce + wiou;
    }
    __syncthreads();
    if (t == 0) {
        float s = 0.0f;
        #pragma unroll
        for (int i = 0; i < NB; ++i) s += ls[i];
        out[0] = s * (1.0f / (float)NB);
    }
}

// ---------------------------------------------------------------------------
extern "C" void kernel_launch(void* const* d_in, const int* in_sizes, int n_in,
                              void* d_out, int out_size, void* d_ws, size_t ws_size,
                              hipStream_t stream)
{
    const float* xin = (const float*)d_in[0];   // "input"  (logits)
    const float* tgt = (const float*)d_in[1];   // "target"
    float* hsum  = (float*)d_ws;                // NB*NPIX floats (18.9 MB)
    float* accum = hsum + (size_t)NB * NPIX;    // 128 floats

    hbox_kernel    <<<(NB * NH) / 4, 256, 0, stream>>>(tgt, hsum, accum);
    fused_kernel   <<<NB * 32,       384, 0, stream>>>(xin, tgt, hsum, accum);
    finalize_kernel<<<1,             64,  0, stream>>>(accum, (float*)d_out);
}